// Round 4
// baseline (2089.109 us; speedup 1.0000x reference)
//
#include <hip/hip_runtime.h>
#include <hip/hip_bf16.h>

// ---------------------------------------------------------------------------
// SemGCN forward, round 4.
//  * Branches 1-4 share weights -> merged into NW-wide launches (NW from
//    ws_size: 4 / 2 / 1). Per-(branch,layer) BN-stats slots.
//  * Heavy kernel: 4 batch elems / block (BPB4), LDS 17 KB, lb(256,5) ->
//    ~5-6 blocks/CU resident and multiple block generations per launch so
//    staging / GEMM / store phases overlap across blocks.
//  * h / R blocked bf16 layout: addr(b,c,i) = b*2048 + (c>>3)*128 + i*8 + (c&7).
//  * Joint-mix via MFMA transpose trick; sliced stats atomics.
// ---------------------------------------------------------------------------

#define BATCH 8192
#define NJ 16
#define FHID 128
#define NROWS (BATCH * NJ)      // 131072
#define NSLICE 32
#define LSTRIDE 8192            // per-layer stats floats = 32*256
#define SB 73728                // per-branch stats stride = 9*LSTRIDE
#define HSTRIDE 16777216        // per-branch h elems = 8192*2048

typedef unsigned short u16;
typedef __attribute__((ext_vector_type(8))) short frag_ab;  // 8 bf16
typedef __attribute__((ext_vector_type(4))) short frag16;   // 4 bf16
typedef __attribute__((ext_vector_type(4))) float frag_cd;  // 4 fp32

__device__ __forceinline__ unsigned short f2bf(float f) {
  unsigned u = __float_as_uint(f);
  u = u + 0x7FFF + ((u >> 16) & 1);  // RNE
  return (unsigned short)(u >> 16);
}
__device__ __forceinline__ float bf2f(unsigned short s) {
  return __uint_as_float((unsigned)s << 16);
}

// H36M 16-joint adjacency + diag, row bitmasks (bit j set if mask[i][j])
__constant__ unsigned short kMaskBits[16] = {
    0x0093, 0x0007, 0x000E, 0x000C, 0x0031, 0x0070, 0x0060, 0x0181,
    0x4B80, 0x0700, 0x0600, 0x1900, 0x3800, 0x3000, 0xC100, 0xC000};

// 15 att slots: 0=in, 1=cat, 2..9=res[0..7], 10..14=out[0..4]
__global__ void att_kernel(const float* __restrict__ e_in,
                           const float* __restrict__ e_cat,
                           const float* __restrict__ e_res,
                           const float* __restrict__ e_out,
                           float* __restrict__ att_off,
                           float* __restrict__ attd) {
  int t = threadIdx.x;
  if (t >= 240) return;
  int m = t >> 4, i = t & 15;
  const float* e;
  if (m == 0) e = e_in;
  else if (m == 1) e = e_cat;
  else if (m < 10) e = e_res + (m - 2) * 256;
  else e = e_out + (m - 10) * 256;
  unsigned msk = kMaskBits[i];
  float mx = -3.0e38f;
  for (int j = 0; j < 16; ++j)
    if ((msk >> j) & 1) mx = fmaxf(mx, e[i * 16 + j]);
  float v[16];
  float s = 0.0f;
  for (int j = 0; j < 16; ++j) {
    float val = ((msk >> j) & 1) ? expf(e[i * 16 + j] - mx) : 0.0f;
    v[j] = val;
    s += val;
  }
  float inv = 1.0f / s;
  for (int j = 0; j < 16; ++j)
    att_off[m * 256 + i * 16 + j] = (j == i) ? 0.0f : v[j] * inv;
  attd[m * 16 + i] = v[i] * inv;
}

// att -> bf16 B-fragments for mfma_16x16x16: B[k=(l>>4)*4+j][n=l&15].
__global__ void pack_attB(const float* __restrict__ att_off,
                          const float* __restrict__ attd,
                          short* __restrict__ attB) {
  int idx = blockIdx.x * 256 + threadIdx.x;
  if (idx >= 15 * 64) return;
  int slot = idx >> 6, lane = idx & 63;
  int n = lane & 15, q = lane >> 4;
  frag16 bd, bo;
#pragma unroll
  for (int j = 0; j < 4; ++j) {
    int k = q * 4 + j;
    bd[j] = (short)f2bf(k == n ? attd[slot * 16 + n] : 0.0f);
    bo[j] = (short)f2bf(att_off[slot * 256 + n * 16 + k]);  // attoff^T[k][n]
  }
  *(frag16*)(attB + slot * 512 + lane * 4) = bd;
  *(frag16*)(attB + slot * 512 + 256 + lane * 4) = bo;
}

// W_res[8][2][128][128] fp32 -> bf16 B-fragments (16x16x32).
__global__ void pack_w_kernel(const float* __restrict__ W_res,
                              short* __restrict__ Wpk) {
  int idx = blockIdx.x * 256 + threadIdx.x;  // 8*64*64 = 32768
  int lane = idx & 63;
  int frag = (idx >> 6) & 63;  // kk*16+nt
  int layer = idx >> 12;
  int kk = frag >> 4, nt = frag & 15;
  int n = nt * 16 + (lane & 15);
  int kbase = kk * 32 + (lane >> 4) * 8;
  int mat = n >> 7, c = n & 127;
  const float* Wsrc = W_res + (((size_t)layer * 2 + mat) * 128) * 128;
  short* dst = Wpk + ((size_t)(layer * 64 + frag)) * 512 + lane * 8;
#pragma unroll
  for (int j = 0; j < 8; ++j)
    dst[j] = (short)f2bf(Wsrc[(size_t)(kbase + j) * 128 + c]);
}

// W_out[5][2][128][3] -> bf16 B-frags, N=16: cols 0-2 = W0, 3-5 = W1, rest 0.
__global__ void pack_wout(const float* __restrict__ W_out,
                          short* __restrict__ Wopk) {
  int idx = blockIdx.x * 256 + threadIdx.x;  // 5*4*64 = 1280
  if (idx >= 1280) return;
  int layer = idx >> 8, rem = idx & 255;
  int kk = rem >> 6, lane = rem & 63;
  int n = lane & 15, q = lane >> 4;
  frag_ab v;
#pragma unroll
  for (int j = 0; j < 8; ++j) {
    int k = kk * 32 + q * 8 + j;
    float val = 0.0f;
    if (n < 3) val = W_out[((size_t)(layer * 2 + 0) * 128 + k) * 3 + n];
    else if (n < 6) val = W_out[((size_t)(layer * 2 + 1) * 128 + k) * 3 + (n - 3)];
    v[j] = (short)f2bf(val);
  }
  *(frag_ab*)(Wopk + ((size_t)(layer * 4 + kk) * 64 + lane) * 8) = v;
}

// ---------------------------------------------------------------------------
// Heavy layer (128x128). Block 256 = 4 waves, 4 batch elems. Grid nbr*2048.
// br = blockIdx>>11 selects the branch's stats slots. In-place h update.
// ---------------------------------------------------------------------------
__launch_bounds__(256, 5)
__global__ void gconv_mfma_kernel(const u16* __restrict__ hin,
                                  const float* __restrict__ stats_in,
                                  const float* __restrict__ gamma,
                                  const float* __restrict__ beta,
                                  u16* __restrict__ resbuf,
                                  int res_mode,
                                  const short* __restrict__ Wpk,   // [4][16][64][8]
                                  const float* __restrict__ bias,  // [128]
                                  const short* __restrict__ attB,  // [2][64][4]
                                  u16* __restrict__ hout,
                                  float* __restrict__ stats_out) {
  __shared__ short Apk[16 * 512];
  __shared__ float sc_s[128], sh_s[128];

  int tid = threadIdx.x;
  int wv = tid >> 6, lane = tid & 63;
  int q = lane >> 4, m = lane & 15;
  int b0 = blockIdx.x * 4;
  int br = blockIdx.x >> 11;
  int slice = blockIdx.x & (NSLICE - 1);
  const float* sin = stats_in + (size_t)br * SB;
  float* sout = stats_out + (size_t)br * SB;

  frag16 bd = *(const frag16*)(attB + lane * 4);
  frag16 boff = *(const frag16*)(attB + 256 + lane * 4);
  float biasr[2][4];
  *(float4*)biasr[0] = *(const float4*)(bias + wv * 16 + q * 4);
  *(float4*)biasr[1] = *(const float4*)(bias + 64 + wv * 16 + q * 4);

  // ---- phase 0: reduce stats slices -> BN scale/shift in LDS ----
  if (tid < 128) {
    float sum = 0.f, sq = 0.f;
#pragma unroll
    for (int s = 0; s < NSLICE; ++s) {
      sum += sin[s * 256 + tid];
      sq += sin[s * 256 + 128 + tid];
    }
    const float invN = 1.0f / (float)NROWS;
    float mu = sum * invN;
    float var = fmaxf(sq * invN - mu * mu, 0.f);
    float sc = gamma[tid] * rsqrtf(var + 1e-5f);
    sc_s[tid] = sc;
    sh_s[tid] = beta[tid] - mu * sc;
  }
  __syncthreads();

  // ---- phase 1: wave wv stages batch elem b0+wv (BN+ReLU+res, bf16) ----
  {
    size_t bb = (size_t)(b0 + wv) * 2048;
#pragma unroll
    for (int kk = 0; kk < 4; ++kk) {
      size_t base = bb + kk * 512 + q * 128 + m * 8;
      frag_ab hv = *(const frag_ab*)(hin + base);
      const float* scp = &sc_s[kk * 32 + q * 8];
      const float* shp = &sh_s[kk * 32 + q * 8];
      float a[8];
#pragma unroll
      for (int e = 0; e < 8; ++e)
        a[e] = fmaxf(0.f, fmaf(bf2f((unsigned short)hv[e]), scp[e], shp[e]));
      if (res_mode & 1) {
        frag_ab rv = *(const frag_ab*)(resbuf + base);
#pragma unroll
        for (int e = 0; e < 8; ++e) a[e] += bf2f((unsigned short)rv[e]);
      }
      frag_ab av;
#pragma unroll
      for (int e = 0; e < 8; ++e) av[e] = (short)f2bf(a[e]);
      *(frag_ab*)&Apk[(wv * 4 + kk) * 512 + lane * 8] = av;
      if (res_mode & 2) *(frag_ab*)(resbuf + base) = av;
    }
  }
  __syncthreads();

  // ---- phase 2: GEMM (4 mt x 16 nt x 4 kk) + MFMA mix epilogue ----
  float ssum[2][4] = {{0.f}}, ssq[2][4] = {{0.f}};
  frag_cd acc[4][4];
#pragma unroll
  for (int mi = 0; mi < 4; ++mi)
#pragma unroll
    for (int t = 0; t < 4; ++t) acc[mi][t] = (frag_cd){0.f, 0.f, 0.f, 0.f};

#pragma unroll
  for (int kk = 0; kk < 4; ++kk) {
    frag_ab bfr[4];
#pragma unroll
    for (int t = 0; t < 4; ++t) {
      int nt = wv + 4 * t;
      bfr[t] = *(const frag_ab*)(Wpk + ((kk * 16 + nt) * 64 + lane) * 8);
    }
#pragma unroll
    for (int mi = 0; mi < 4; ++mi) {
      frag_ab af = *(const frag_ab*)&Apk[(mi * 4 + kk) * 512 + lane * 8];
#pragma unroll
      for (int t = 0; t < 4; ++t)
        acc[mi][t] = __builtin_amdgcn_mfma_f32_16x16x32_bf16(af, bfr[t],
                                                             acc[mi][t], 0, 0, 0);
    }
  }

  // epilogue: Out^T = Y0^T*Bd + Y1^T*Boff + bias; store blocked bf16
#pragma unroll
  for (int mi = 0; mi < 4; ++mi) {
    size_t bb = (size_t)(b0 + mi) * 2048;
#pragma unroll
    for (int p = 0; p < 2; ++p) {
      frag16 a0, a1;
#pragma unroll
      for (int r = 0; r < 4; ++r) {
        a0[r] = (short)f2bf(acc[mi][p][r]);
        a1[r] = (short)f2bf(acc[mi][p + 2][r]);
      }
      frag_cd d = (frag_cd){0.f, 0.f, 0.f, 0.f};
      d = __builtin_amdgcn_mfma_f32_16x16x16bf16_1k(a0, bd, d, 0, 0, 0);
      d = __builtin_amdgcn_mfma_f32_16x16x16bf16_1k(a1, boff, d, 0, 0, 0);
      int colbase = (p == 0) ? wv * 16 : 64 + wv * 16;
      frag16 sv;
#pragma unroll
      for (int r = 0; r < 4; ++r) {
        float v = d[r] + biasr[p][r];
        ssum[p][r] += v;
        ssq[p][r] = fmaf(v, v, ssq[p][r]);
        sv[r] = (short)f2bf(v);
      }
      size_t addr = bb + (size_t)(colbase / 8 + (q >> 1)) * 128 + m * 8 + (q & 1) * 4;
      *(frag16*)(hout + addr) = sv;
    }
  }

  // ---- phase 3: BN stats (cross-joint shuffle reduce, sliced atomics) ----
#pragma unroll
  for (int p = 0; p < 2; ++p)
#pragma unroll
    for (int r = 0; r < 4; ++r) {
      float v1 = ssum[p][r], v2 = ssq[p][r];
      v1 += __shfl_xor(v1, 1); v2 += __shfl_xor(v2, 1);
      v1 += __shfl_xor(v1, 2); v2 += __shfl_xor(v2, 2);
      v1 += __shfl_xor(v1, 4); v2 += __shfl_xor(v2, 4);
      v1 += __shfl_xor(v1, 8); v2 += __shfl_xor(v2, 8);
      if (m == 0) {
        int c = ((p == 0) ? wv * 16 : 64 + wv * 16) + q * 4 + r;
        atomicAdd(&sout[slice * 256 + c], v1);
        atomicAdd(&sout[slice * 256 + 128 + c], v2);
      }
    }
}

// ---------------------------------------------------------------------------
// Small-K layers (Fin=2, Fin=12): fp32 VALU, blocked bf16 output via LDS.
// Grid nbr*4096; br = blockIdx>>12 picks input pointer / stats / h region.
// ---------------------------------------------------------------------------
template <int FIN>
__launch_bounds__(256)
__global__ void gconv_kernel(const float* __restrict__ x0,
                             const float* __restrict__ x1,
                             const float* __restrict__ x2,
                             const float* __restrict__ x3,
                             const float* __restrict__ W,     // [2][FIN][128]
                             const float* __restrict__ bias,  // [128]
                             const float* __restrict__ attoff,
                             const float* __restrict__ attd_p,
                             u16* __restrict__ hout,          // blocked bf16
                             float* __restrict__ stats_out) {
  __shared__ float xin[2][NJ][FIN];
  __shared__ float att_s[256];
  __shared__ float attd_s[16];
  __shared__ float red[256];
  __shared__ short xout[2][NJ][128];

  int tid = threadIdx.x;
  int br = blockIdx.x >> 12;
  int b0 = (blockIdx.x & 4095) * 2;
  int slice = blockIdx.x & (NSLICE - 1);
  const float* hin = (br == 0) ? x0 : (br == 1) ? x1 : (br == 2) ? x2 : x3;
  u16* hob = hout + (size_t)br * HSTRIDE;
  float* sout = stats_out + (size_t)br * SB;

  att_s[tid] = attoff[tid];
  if (tid < 16) attd_s[tid] = attd_p[tid];

  const int TOT4 = 2 * NJ * FIN / 4;
  const float4* hin4 = (const float4*)(hin + (size_t)b0 * NJ * FIN);
  for (int k = tid; k < TOT4; k += 256)
    ((float4*)&xin[0][0][0])[k] = hin4[k];
  __syncthreads();

  int o = tid & 127;
  int bl = tid >> 7;
  float acc0[16], acc1[16];
#pragma unroll
  for (int j = 0; j < 16; ++j) { acc0[j] = 0.0f; acc1[j] = 0.0f; }
  const float* W0 = W;
  const float* W1 = W + FIN * FHID;
  if constexpr (FIN % 4 == 0) {
    for (int f = 0; f < FIN; f += 4) {
      float w00 = W0[(f + 0) * FHID + o], w01 = W0[(f + 1) * FHID + o];
      float w02 = W0[(f + 2) * FHID + o], w03 = W0[(f + 3) * FHID + o];
      float w10 = W1[(f + 0) * FHID + o], w11 = W1[(f + 1) * FHID + o];
      float w12 = W1[(f + 2) * FHID + o], w13 = W1[(f + 3) * FHID + o];
#pragma unroll
      for (int j = 0; j < 16; ++j) {
        float4 xv = *(const float4*)&xin[bl][j][f];
        acc0[j] = fmaf(xv.x, w00, fmaf(xv.y, w01, fmaf(xv.z, w02, fmaf(xv.w, w03, acc0[j]))));
        acc1[j] = fmaf(xv.x, w10, fmaf(xv.y, w11, fmaf(xv.z, w12, fmaf(xv.w, w13, acc1[j]))));
      }
    }
  } else {
    for (int f = 0; f < FIN; ++f) {
      float w0 = W0[f * FHID + o], w1 = W1[f * FHID + o];
#pragma unroll
      for (int j = 0; j < 16; ++j) {
        float xv = xin[bl][j][f];
        acc0[j] = fmaf(xv, w0, acc0[j]);
        acc1[j] = fmaf(xv, w1, acc1[j]);
      }
    }
  }

  float bo = bias[o];
  float ssum = 0.0f, ssq = 0.0f;
#pragma unroll
  for (int i = 0; i < 16; ++i) {
    float h = fmaf(attd_s[i], acc0[i], bo);
#pragma unroll
    for (int j = 0; j < 16; ++j) h = fmaf(att_s[i * 16 + j], acc1[j], h);
    xout[bl][i][o] = (short)f2bf(h);
    ssum += h;
    ssq = fmaf(h, h, ssq);
  }
  __syncthreads();
  red[tid] = ssum;
  __syncthreads();
  if (bl == 0) atomicAdd(&sout[slice * 256 + o], ssum + red[o + 128]);
  __syncthreads();
  red[tid] = ssq;
  __syncthreads();
  if (bl == 0) atomicAdd(&sout[slice * 256 + 128 + o], ssq + red[o + 128]);
  __syncthreads();

  for (int qq = tid; qq < 512; qq += 256) {
    int b_l = qq >> 8, g = (qq >> 4) & 15, ii = qq & 15;
    *(frag_ab*)(hob + (size_t)(b0 + b_l) * 2048 + g * 128 + ii * 8) =
        *(const frag_ab*)&xout[b_l][ii][g * 8];
  }
}

// ---------------------------------------------------------------------------
// Output gconv (Fout=3) via MFMA, N=16. Grid nbr*1024; local = blockIdx>>10.
// All per-branch bases are pre-offset to the group's first branch.
// ---------------------------------------------------------------------------
__launch_bounds__(256, 4)
__global__ void gconv_out_kernel(const u16* __restrict__ hin,
                                 const float* __restrict__ stats_in,
                                 const float* __restrict__ gamma,
                                 const float* __restrict__ beta,
                                 const u16* __restrict__ resbuf,
                                 const short* __restrict__ Wopk,  // [4][64][8] per slot
                                 const float* __restrict__ bias3, // [3] per slot
                                 const float* __restrict__ attoff,
                                 const float* __restrict__ attd_p,
                                 float* __restrict__ outb,        // [B,16,3] per slot
                                 int outstride) {
  __shared__ float sc_s[128], sh_s[128];
  __shared__ float att_s[256];
  __shared__ float attd_s[16];
  __shared__ float ys[4][6][16];

  int tid = threadIdx.x;
  int wv = tid >> 6, lane = tid & 63;
  int q = lane >> 4, m = lane & 15;
  int local = blockIdx.x >> 10;
  int b0 = (blockIdx.x & 1023) * 8;

  const u16* hb = hin + (size_t)local * HSTRIDE;
  const u16* rb = resbuf + (size_t)local * HSTRIDE;
  const float* sin = stats_in + (size_t)local * SB;
  const short* Wo = Wopk + (size_t)local * 2048;
  const float* bs = bias3 + (size_t)local * 3;
  const float* ao = attoff + (size_t)local * 256;
  const float* ad = attd_p + (size_t)local * 16;
  float* out = outb + (size_t)local * outstride;

  att_s[tid] = ao[tid];
  if (tid < 16) attd_s[tid] = ad[tid];
  if (tid < 128) {
    float sum = 0.f, sq = 0.f;
#pragma unroll
    for (int s = 0; s < NSLICE; ++s) {
      sum += sin[s * 256 + tid];
      sq += sin[s * 256 + 128 + tid];
    }
    const float invN = 1.0f / (float)NROWS;
    float mu = sum * invN;
    float var = fmaxf(sq * invN - mu * mu, 0.f);
    float sc = gamma[tid] * rsqrtf(var + 1e-5f);
    sc_s[tid] = sc;
    sh_s[tid] = beta[tid] - mu * sc;
  }
  __syncthreads();

  frag_ab bfr[4];
#pragma unroll
  for (int kk = 0; kk < 4; ++kk)
    bfr[kk] = *(const frag_ab*)(Wo + (kk * 64 + lane) * 8);

  for (int mi = 0; mi < 2; ++mi) {
    int b = b0 + wv * 2 + mi;
    size_t bb = (size_t)b * 2048;
    frag_cd acc = (frag_cd){0.f, 0.f, 0.f, 0.f};
#pragma unroll
    for (int kk = 0; kk < 4; ++kk) {
      size_t base = bb + kk * 512 + q * 128 + m * 8;
      frag_ab hv = *(const frag_ab*)(hb + base);
      frag_ab rv = *(const frag_ab*)(rb + base);
      const float* scp = &sc_s[kk * 32 + q * 8];
      const float* shp = &sh_s[kk * 32 + q * 8];
      frag_ab av;
#pragma unroll
      for (int e = 0; e < 8; ++e) {
        float a = fmaxf(0.f, fmaf(bf2f((unsigned short)hv[e]), scp[e], shp[e])) +
                  bf2f((unsigned short)rv[e]);
        av[e] = (short)f2bf(a);
      }
      acc = __builtin_amdgcn_mfma_f32_16x16x32_bf16(av, bfr[kk], acc, 0, 0, 0);
    }
    if (m < 6) {
#pragma unroll
      for (int r = 0; r < 4; ++r) ys[wv][m][q * 4 + r] = acc[r];
    }
    // same-wave LDS ops are in-order; no barrier needed
    if (q < 3) {
      float v = bs[q] + attd_s[m] * ys[wv][q][m];
#pragma unroll
      for (int j = 0; j < 16; ++j) v = fmaf(att_s[m * 16 + j], ys[wv][3 + q][j], v);
      out[((size_t)b * 16 + m) * 3 + q] = v;
    }
  }
}

// merged[b,j,c] = out_{1+c/3}[b,j,c%3]; out_i at d_out + i*393216
__global__ void pack_merged(const float* __restrict__ dout, float* __restrict__ merged) {
  int idx = blockIdx.x * 256 + threadIdx.x;
  if (idx >= BATCH * NJ * 12) return;
  int c = idx % 12;
  int bj = idx / 12;
  merged[idx] = dout[(size_t)(1 + c / 3) * 393216 + (size_t)bj * 3 + (c % 3)];
}

extern "C" void kernel_launch(void* const* d_in, const int* in_sizes, int n_in,
                              void* d_out, int out_size, void* d_ws, size_t ws_size,
                              hipStream_t stream) {
  (void)in_sizes; (void)n_in; (void)out_size;
  const float* W_in = (const float*)d_in[4];
  const float* b_in = (const float*)d_in[5];
  const float* e_in = (const float*)d_in[6];
  const float* g_in = (const float*)d_in[7];
  const float* beta_in = (const float*)d_in[8];
  const float* W_cat = (const float*)d_in[9];
  const float* b_cat = (const float*)d_in[10];
  const float* e_cat = (const float*)d_in[11];
  const float* g_cat = (const float*)d_in[12];
  const float* beta_cat = (const float*)d_in[13];
  const float* W_res = (const float*)d_in[14];
  const float* b_res = (const float*)d_in[15];
  const float* e_res = (const float*)d_in[16];
  const float* g_res = (const float*)d_in[17];
  const float* beta_res = (const float*)d_in[18];
  const float* W_out = (const float*)d_in[19];
  const float* b_out = (const float*)d_in[20];
  const float* e_out = (const float*)d_in[21];

  float* ws = (float*)d_ws;
  float* att_off = ws;                        // 3840 f
  float* attd = att_off + 3840;               // 256 f
  short* attB = (short*)(attd + 256);         // 7680 sh
  short* Wpk = attB + 7680;                   // 262144 sh
  short* Wopk = Wpk + 262144;                 // 10240 sh
  float* stats = (float*)(Wopk + 10240);      // 5*SB f
  float* merged = stats + 5 * SB;             // 1572864 f
  u16* hbuf = (u16*)(merged + 1572864);
  size_t head = (size_t)((char*)hbuf - (char*)ws);

  // pick branch-group width from available scratch (deterministic per problem)
  int NW = 1;
  if (ws_size >= head + (size_t)8 * HSTRIDE * 2) NW = 4;
  else if (ws_size >= head + (size_t)4 * HSTRIDE * 2) NW = 2;
  u16* R = hbuf + (size_t)NW * HSTRIDE;

  hipMemsetAsync(stats, 0, (size_t)5 * SB * sizeof(float), stream);
  att_kernel<<<1, 256, 0, stream>>>(e_in, e_cat, e_res, e_out, att_off, attd);
  pack_attB<<<4, 256, 0, stream>>>(att_off, attd, attB);
  pack_w_kernel<<<128, 256, 0, stream>>>(W_res, Wpk);
  pack_wout<<<5, 256, 0, stream>>>(W_out, Wopk);

  float* dout = (float*)d_out;

  // run one group of branches [first, first+nbr) (or the cat branch)
  auto run_group = [&](int first, int nbr, bool iscat) {
    int sbr = iscat ? 4 : first;           // stats branch base
    int oslot = iscat ? 4 : first;         // out-layer slot base
    float* st = stats + (size_t)sbr * SB;
    if (iscat) {
      gconv_kernel<12><<<4096, 256, 0, stream>>>(
          merged, merged, merged, merged, W_cat, b_cat, att_off + 256, attd + 16,
          hbuf, st);
    } else {
      const float* xs[4];
      for (int i = 0; i < 4; ++i) xs[i] = (const float*)d_in[first + ((i < nbr) ? i : 0)];
      gconv_kernel<2><<<nbr * 4096, 256, 0, stream>>>(
          xs[0], xs[1], xs[2], xs[3], W_in, b_in, att_off, attd, hbuf, st);
    }
    for (int k = 0; k < 8; ++k) {
      const float* gg = (k == 0) ? (iscat ? g_cat : g_in) : g_res + (size_t)(k - 1) * FHID;
      const float* bb = (k == 0) ? (iscat ? beta_cat : beta_in) : beta_res + (size_t)(k - 1) * FHID;
      int rm = (k == 0) ? 2 : ((k % 2 == 0) ? 3 : 0);
      gconv_mfma_kernel<<<nbr * 2048, 256, 0, stream>>>(
          hbuf, st + (size_t)k * LSTRIDE, gg, bb, R, rm,
          Wpk + (size_t)k * 32768, b_res + (size_t)k * FHID,
          attB + (size_t)(2 + k) * 512, hbuf, st + (size_t)(k + 1) * LSTRIDE);
    }
    float* outb = iscat ? dout : dout + (size_t)(1 + first) * 393216;
    gconv_out_kernel<<<nbr * 1024, 256, 0, stream>>>(
        hbuf, st + (size_t)8 * LSTRIDE, g_res + 7 * FHID, beta_res + 7 * FHID, R,
        Wopk + (size_t)oslot * 2048, b_out + (size_t)oslot * 3,
        att_off + (size_t)(10 + oslot) * 256, attd + (size_t)(10 + oslot) * 16,
        outb, iscat ? 0 : 393216);
  };

  for (int first = 0; first < 4; first += NW) run_group(first, NW, false);
  pack_merged<<<(BATCH * NJ * 12 + 255) / 256, 256, 0, stream>>>(dout, merged);
  run_group(0, 1, true);
}